// Round 4
// baseline (78.867 us; speedup 1.0000x reference)
//
#include <hip/hip_runtime.h>

// Gravity field: F[b,i,:] = G*m_i*mask_i * sum_j (m_j*mask_j)*(p_j-p_i)/max(|p_j-p_i|,1e-4)^3
// - Diagonal: diff==0 exactly; clamp keeps 1/d^3 finite; s*0 = 0 -> no branch.
// - max(sqrt(r2),eps) == sqrt(max(r2,eps^2)) -> one v_rsq_f32 (bare, via builtin) + v_max_f32.
// - Two-phase (partials in d_ws + reduce): avoids 1.5M+ serializing L2 atomics and the
//   d_out memset dispatch (reduce overwrites d_out fully).
// - IPT=4, TJ=32: one ds_read_b128 (12 cy, per-CU pipe shared by 4 SIMDs) feeds ~136 cy
//   of VALU (LDS pipe ~24% duty), 16 independent pair-chains (4 i's x unroll 4) hide
//   the ~120 cy LDS latency + rsq latency.
// - jsplit=128 keeps grid at 1024 blocks (4 blocks/CU, 16 waves/CU) -- the occupancy
//   that measured best (R2's 8 waves/CU cost +5 us).

#define TI  256   // threads per block
#define IPT 4     // i-values per thread
#define TJ  32    // bodies-j per block (staged in LDS)

__global__ __launch_bounds__(TI) void gravity_partial_kernel(
    const float* __restrict__ pos,    // (B, N, 3)
    const float* __restrict__ mass,   // (B, N, 1)
    const float* __restrict__ Gp,     // (1,)
    const float* __restrict__ mask,   // (B, N)
    float* __restrict__ part,         // (jsplit, B*N*3) workspace
    int N, int jsplit)
{
    __shared__ float4 sj[TJ];

    const int ib      = TI * IPT;            // 1024 i's per block
    const int tiles_i = N / ib;              // 4
    const int per_b   = tiles_i * jsplit;    // 512
    const int bid     = blockIdx.x;
    const int b       = bid / per_b;
    const int rem     = bid - b * per_b;
    const int it      = rem / jsplit;
    const int jc      = rem - it * jsplit;
    const int tid     = threadIdx.x;

    const float* posb  = pos  + (size_t)b * N * 3;
    const float* massb = mass + (size_t)b * N;
    const float* maskb = mask + (size_t)b * N;

    // Stage j-tile: position + (mass*mask) packed as float4.
    if (tid < TJ) {
        const int j = jc * TJ + tid;
        float4 v;
        v.x = posb[j * 3 + 0];
        v.y = posb[j * 3 + 1];
        v.z = posb[j * 3 + 2];
        v.w = massb[j] * maskb[j];
        sj[tid] = v;
    }

    const float g = Gp[0];
    int   iv[IPT];
    float pix[IPT], piy[IPT], piz[IPT], wi[IPT];
#pragma unroll
    for (int u = 0; u < IPT; ++u) {
        const int i = it * ib + u * TI + tid;
        iv[u]  = i;
        pix[u] = posb[i * 3 + 0];
        piy[u] = posb[i * 3 + 1];
        piz[u] = posb[i * 3 + 2];
        wi[u]  = g * massb[i] * maskb[i];
    }

    __syncthreads();

    float fx[IPT], fy[IPT], fz[IPT];
#pragma unroll
    for (int u = 0; u < IPT; ++u) { fx[u] = 0.f; fy[u] = 0.f; fz[u] = 0.f; }

#pragma unroll 4
    for (int k = 0; k < TJ; ++k) {
        const float4 pj = sj[k];          // broadcast LDS read (all lanes same addr)
#pragma unroll
        for (int u = 0; u < IPT; ++u) {
            const float dx = pj.x - pix[u];
            const float dy = pj.y - piy[u];
            const float dz = pj.z - piz[u];
            float r2 = fmaf(dx, dx, fmaf(dy, dy, dz * dz));
            r2 = fmaxf(r2, 1e-8f);        // = (max(dist, 1e-4))^2
            const float ir = __builtin_amdgcn_rsqf(r2);
            const float s  = pj.w * (ir * ir * ir);
            fx[u] = fmaf(s, dx, fx[u]);
            fy[u] = fmaf(s, dy, fy[u]);
            fz[u] = fmaf(s, dz, fz[u]);
        }
    }

    // Plain stores to this block's private partial slice (no atomics).
    const int B = gridDim.x / per_b;
    const size_t total = (size_t)B * N * 3;
    float* pbase = part + (size_t)jc * total;
#pragma unroll
    for (int u = 0; u < IPT; ++u) {
        float* o = pbase + ((size_t)b * N + iv[u]) * 3;
        o[0] = fx[u] * wi[u];
        o[1] = fy[u] * wi[u];
        o[2] = fz[u] * wi[u];
    }
}

__global__ __launch_bounds__(256) void gravity_reduce_kernel(
    const float* __restrict__ part,   // (jsplit, total)
    float* __restrict__ out,          // (total)
    int total, int jsplit)
{
    const int idx = blockIdx.x * 256 + threadIdx.x;
    if (idx >= total) return;
    float s = 0.f;
#pragma unroll 16
    for (int jc = 0; jc < jsplit; ++jc)
        s += part[(size_t)jc * total + idx];
    out[idx] = s;
}

extern "C" void kernel_launch(void* const* d_in, const int* in_sizes, int n_in,
                              void* d_out, int out_size, void* d_ws, size_t ws_size,
                              hipStream_t stream)
{
    const float* pos  = (const float*)d_in[0];
    const float* mass = (const float*)d_in[1];
    const float* Gp   = (const float*)d_in[2];
    const float* mask = (const float*)d_in[3];
    float* out  = (float*)d_out;
    float* part = (float*)d_ws;

    const int N = 4096;                 // fixed problem shape
    const int B = in_sizes[3] / N;      // mask is (B, N)
    const int jsplit = N / TJ;          // 128 j-chunks

    const int grid = B * (N / (TI * IPT)) * jsplit;   // 2 * 4 * 128 = 1024 blocks
    gravity_partial_kernel<<<grid, TI, 0, stream>>>(pos, mass, Gp, mask, part, N, jsplit);

    const int total = B * N * 3;        // 24576
    gravity_reduce_kernel<<<(total + 255) / 256, 256, 0, stream>>>(part, out, total, jsplit);
}

// Round 5
// 76.725 us; speedup vs baseline: 1.0279x; 1.0279x over previous
//
#include <hip/hip_runtime.h>

// Gravity field: F[b,i,:] = G*m_i*mask_i * sum_j (m_j*mask_j)*(p_j-p_i)/max(|p_j-p_i|,1e-4)^3
// R5: scalar-operand inner loop.
// - Pre-pass packs (x, y, z, m*mask) per body into float4 in d_ws.
// - Main kernel reads j-bodies at WAVE-UNIFORM addresses (derived only from
//   blockIdx + loop counter) from a const __restrict__ pointer -> compiler's
//   divergence analysis lowers them to s_load (SMEM pipe, j-body = 4 SGPRs).
//   Inner loop is then pure VALU: 14 ops/pair (3 sub + 3 fma + max + v_rsq +
//   3 mul + 3 fma), each reading <=1 SGPR (legal). No LDS, no syncthreads.
// - Diagonal: diff==0 exactly; clamp keeps 1/d^3 finite; s*0 = 0 -> no branch.
// - max(sqrt(r2),eps) == sqrt(max(r2,eps^2)) -> one bare v_rsq_f32 + v_max_f32.
// - Two-phase partials (no atomics); reduce overwrites d_out (no memset).
// - IPT=2, TJ=64, jsplit=64 -> grid 1024 (4 blocks/CU, 16 waves/CU = measured best).
// VALU floor: 33.5M pairs / 64 lanes * 28 cy / 1024 SIMDs / 2.4GHz = 6.4 us.

#define TI  256
#define IPT 2
#define TJ  64

__global__ __launch_bounds__(256) void pack_kernel(
    const float* __restrict__ pos,    // (B, N, 3)
    const float* __restrict__ mass,   // (B, N, 1)
    const float* __restrict__ mask,   // (B, N)
    float4* __restrict__ packed,      // (B*N)
    int total)                        // B*N
{
    const int idx = blockIdx.x * 256 + threadIdx.x;
    if (idx >= total) return;
    float4 v;
    v.x = pos[idx * 3 + 0];
    v.y = pos[idx * 3 + 1];
    v.z = pos[idx * 3 + 2];
    v.w = mass[idx] * mask[idx];
    packed[idx] = v;
}

__global__ __launch_bounds__(TI) void gravity_main_kernel(
    const float4* __restrict__ packed, // (B, N)
    const float* __restrict__ Gp,      // (1,)
    float* __restrict__ part,          // (jsplit, B*N*3)
    int N, int jsplit)
{
    const int ib      = TI * IPT;            // 512 i's per block
    const int tiles_i = N / ib;              // 8
    const int per_b   = tiles_i * jsplit;    // 512
    const int bid     = blockIdx.x;
    const int b       = bid / per_b;
    const int rem     = bid - b * per_b;
    const int it      = rem / jsplit;
    const int jc      = rem - it * jsplit;
    const int tid     = threadIdx.x;

    const float4* pb      = packed + (size_t)b * N;
    const float4* pj_base = pb + jc * TJ;    // wave-uniform base

    const int i0 = it * ib + tid;
    const int i1 = i0 + TI;
    const float4 pi0 = pb[i0];               // coalesced 16B per-i data
    const float4 pi1 = pb[i1];

    float fx0 = 0.f, fy0 = 0.f, fz0 = 0.f;
    float fx1 = 0.f, fy1 = 0.f, fz1 = 0.f;

#pragma unroll 8
    for (int k = 0; k < TJ; ++k) {
        const float4 pj = pj_base[k];        // uniform address -> s_load (SGPRs)

        const float dx0 = pj.x - pi0.x;
        const float dy0 = pj.y - pi0.y;
        const float dz0 = pj.z - pi0.z;
        float r20 = fmaf(dx0, dx0, fmaf(dy0, dy0, dz0 * dz0));
        r20 = fmaxf(r20, 1e-8f);             // = (max(dist, 1e-4))^2
        const float ir0 = __builtin_amdgcn_rsqf(r20);
        const float s0  = pj.w * (ir0 * ir0 * ir0);
        fx0 = fmaf(s0, dx0, fx0);
        fy0 = fmaf(s0, dy0, fy0);
        fz0 = fmaf(s0, dz0, fz0);

        const float dx1 = pj.x - pi1.x;
        const float dy1 = pj.y - pi1.y;
        const float dz1 = pj.z - pi1.z;
        float r21 = fmaf(dx1, dx1, fmaf(dy1, dy1, dz1 * dz1));
        r21 = fmaxf(r21, 1e-8f);
        const float ir1 = __builtin_amdgcn_rsqf(r21);
        const float s1  = pj.w * (ir1 * ir1 * ir1);
        fx1 = fmaf(s1, dx1, fx1);
        fy1 = fmaf(s1, dy1, fy1);
        fz1 = fmaf(s1, dz1, fz1);
    }

    const float g   = Gp[0];
    const float wi0 = g * pi0.w;
    const float wi1 = g * pi1.w;

    const int B = gridDim.x / per_b;
    const size_t total = (size_t)B * N * 3;
    float* pbase = part + (size_t)jc * total;
    float* o0 = pbase + ((size_t)b * N + i0) * 3;
    o0[0] = fx0 * wi0;
    o0[1] = fy0 * wi0;
    o0[2] = fz0 * wi0;
    float* o1 = pbase + ((size_t)b * N + i1) * 3;
    o1[0] = fx1 * wi1;
    o1[1] = fy1 * wi1;
    o1[2] = fz1 * wi1;
}

__global__ __launch_bounds__(256) void gravity_reduce_kernel(
    const float* __restrict__ part,   // (jsplit, total)
    float* __restrict__ out,          // (total)
    int total, int jsplit)
{
    const int idx = blockIdx.x * 256 + threadIdx.x;
    if (idx >= total) return;
    float s = 0.f;
#pragma unroll 16
    for (int jc = 0; jc < jsplit; ++jc)
        s += part[(size_t)jc * total + idx];
    out[idx] = s;
}

extern "C" void kernel_launch(void* const* d_in, const int* in_sizes, int n_in,
                              void* d_out, int out_size, void* d_ws, size_t ws_size,
                              hipStream_t stream)
{
    const float* pos  = (const float*)d_in[0];
    const float* mass = (const float*)d_in[1];
    const float* Gp   = (const float*)d_in[2];
    const float* mask = (const float*)d_in[3];
    float* out = (float*)d_out;

    const int N = 4096;                 // fixed problem shape
    const int B = in_sizes[3] / N;      // mask is (B, N)
    const int jsplit = N / TJ;          // 64
    const int nb = B * N;               // 8192 bodies

    // Workspace layout: [0, nb*16) packed float4; then partials.
    float4* packed = (float4*)d_ws;
    float*  part   = (float*)((char*)d_ws + (size_t)nb * sizeof(float4));

    pack_kernel<<<(nb + 255) / 256, 256, 0, stream>>>(pos, mass, mask, packed, nb);

    const int grid = B * (N / (TI * IPT)) * jsplit;   // 2 * 8 * 64 = 1024 blocks
    gravity_main_kernel<<<grid, TI, 0, stream>>>(packed, Gp, part, N, jsplit);

    const int total = B * N * 3;        // 24576
    gravity_reduce_kernel<<<(total + 255) / 256, 256, 0, stream>>>(part, out, total, jsplit);
}